// Round 3
// baseline (281.632 us; speedup 1.0000x reference)
//
#include <hip/hip_runtime.h>
#include <hip/hip_bf16.h>

#define NB 1024
#define LL 4096
#define PP 8192
#define LOGP 13

// Fused: bounded_random_walk -> batch_smooth -> detrend/normalize -> omit*scale
//        -> sim2acquired (linear interp) -> hilbert (radix-2 FFT in LDS)
//        -> write (flip(raw), raw) as FP32.
// All per-row work in ONE block (row n = blockIdx.x). LDS plan (64 KB total):
//   phase A (walk/smooth): cs[4097] @ bf[0..4096], tmp[256] @ bf[4098..4353],
//                          shv[2] @ bf[4356..4357]   (all alias into buf)
//   phase B: bb row (4096 floats) stored at bf[2t+1] (imag slots), then
//            interp into registers, then buf[j]=(val,0), then FFT in buf.
__global__ __launch_bounds__(256) void k_all(
    const float* __restrict__ g_start,
    const float* __restrict__ g_end,
    const float* __restrict__ g_std,
    const float* __restrict__ g_low,
    const float* __restrict__ g_up,
    const int*   __restrict__ g_win,
    const float* __restrict__ g_scale,
    const float* __restrict__ g_noise,
    const float* __restrict__ g_omit,
    const float* __restrict__ g_ppm,
    const float* __restrict__ g_ppmr,
    float* __restrict__ g_out)
{
    __shared__ float2 buf[PP];          // 64 KB exactly
    float* bf  = (float*)buf;
    float* cs  = bf;                    // 4097 floats
    float* tmp = bf + 4098;             // 256 floats
    float* shv = bf + 4356;             // 2 floats

    const int n   = blockIdx.x;
    const int tid = threadIdx.x;
    const float st = g_start[n];
    const float en = g_end[n];
    const float sd = g_std[n];
    const float lo = g_low[n];
    const float up = g_up[n];
    const int   w  = g_win[n];
    const float inv_nm1 = 1.0f / (float)(LL - 1);

    // ---- load 16 fp32 noise steps/thread ----
    float v[16];
    {
        const float4* p = (const float4*)(g_noise + (size_t)n * LL) + (size_t)tid * 4;
#pragma unroll
        for (int q = 0; q < 4; q++) {
            float4 t4 = p[q];
            v[4*q+0] = t4.x; v[4*q+1] = t4.y; v[4*q+2] = t4.z; v[4*q+3] = t4.w;
        }
    }
#pragma unroll
    for (int k = 0; k < 16; k++) v[k] = sd * (v[k] - 0.5f);

    // ---- scan #1: rand = inclusive cumsum(steps) ----
    float run = 0.0f;
#pragma unroll
    for (int k = 0; k < 16; k++) { run += v[k]; v[k] = run; }
    tmp[tid] = run; __syncthreads();
    for (int off = 1; off < 256; off <<= 1) {
        float a = tmp[tid];
        float b = (tid >= off) ? tmp[tid - off] : 0.0f;
        __syncthreads();
        tmp[tid] = a + b;
        __syncthreads();
    }
    float excl = tmp[tid] - run;
    if (tid == 0)   shv[0] = v[0];        // rand[0]
    if (tid == 255) shv[1] = tmp[255];    // rand[L-1]
    __syncthreads();
    const float r0 = shv[0], rT = shv[1];
    __syncthreads();

    // ---- detrend walk, min/max ----
    float del[16];
    float mx = -INFINITY, mn = INFINITY;
#pragma unroll
    for (int k = 0; k < 16; k++) {
        int t = tid * 16 + k;
        float d = (excl + v[k]) - (r0 + (rT - r0) * ((float)t * inv_nm1));
        del[k] = d;
        mx = fmaxf(mx, d); mn = fminf(mn, d);
    }
    tmp[tid] = mx; __syncthreads();
    for (int off = 128; off > 0; off >>= 1) { if (tid < off) tmp[tid] = fmaxf(tmp[tid], tmp[tid + off]); __syncthreads(); }
    mx = tmp[0]; __syncthreads();
    tmp[tid] = mn; __syncthreads();
    for (int off = 128; off > 0; off >>= 1) { if (tid < off) tmp[tid] = fminf(tmp[tid], tmp[tid + off]); __syncthreads(); }
    mn = tmp[0]; __syncthreads();

    const float qs = fmaxf(1.0f, (mx - mn) / (up - lo));

    // ---- squeeze + reflect + trend -> walk values ----
    float wv[16];
#pragma unroll
    for (int k = 0; k < 16; k++) {
        int t = tid * 16 + k;
        float tr  = st + (en - st) * ((float)t * inv_nm1);
        float ub  = up - tr;
        float lb2 = lo - tr;
        float d = del[k] / qs;
        float over = d - ub;
        d = (over >= 0.0f) ? (ub - over) : d;
        float under = lb2 - d;
        d = (under >= 0.0f) ? (lb2 + under) : d;
        wv[k] = tr + d;
    }

    // ---- scan #2: exclusive cumsum of walk -> cs[0..LL] ----
    run = 0.0f;
#pragma unroll
    for (int k = 0; k < 16; k++) { float x = wv[k]; run += x; wv[k] = run; }
    tmp[tid] = run; __syncthreads();
    for (int off = 1; off < 256; off <<= 1) {
        float a = tmp[tid];
        float b = (tid >= off) ? tmp[tid - off] : 0.0f;
        __syncthreads();
        tmp[tid] = a + b;
        __syncthreads();
    }
    float excl2 = tmp[tid] - run;
    float grand2 = tmp[255];
    __syncthreads();
#pragma unroll
    for (int k = 0; k < 16; k++) {
        int t = tid * 16 + k;
        cs[t] = excl2 + ((k == 0) ? 0.0f : wv[k - 1]);
    }
    if (tid == 255) cs[LL] = grand2;
    __syncthreads();

    // ---- box smooth (zero-padded via clamped exclusive cumsum) ----
    const int w2 = w / 2;
    const float invw = 1.0f / (float)w;
    float bvals[16];
#pragma unroll
    for (int k = 0; k < 16; k++) {
        int t  = tid * 16 + k;
        int li = t - w2;
        int hi = li + w;
        li = (li < 0) ? 0 : li;
        hi = (hi > LL) ? LL : hi;
        bvals[k] = (cs[hi] - cs[li]) * invw;
    }
    if (tid == 0)   shv[0] = bvals[0];
    if (tid == 255) shv[1] = bvals[15];
    __syncthreads();
    const float b0 = shv[0], bL = shv[1];

    // ---- detrend #2 + absmax-normalize ----
    float am = 0.0f;
#pragma unroll
    for (int k = 0; k < 16; k++) {
        int t = tid * 16 + k;
        bvals[k] -= b0 + (bL - b0) * ((float)t * inv_nm1);
        am = fmaxf(am, fabsf(bvals[k]));
    }
    tmp[tid] = am; __syncthreads();
    for (int off = 128; off > 0; off >>= 1) { if (tid < off) tmp[tid] = fmaxf(tmp[tid], tmp[tid + off]); __syncthreads(); }
    float denom = tmp[0];
    denom = (denom == 0.0f) ? 1.0f : denom;
    const float fac = g_omit[n] * g_scale[n] / denom;
    __syncthreads();   // all cs/tmp reads done before bb overwrites aliased slots

    // ---- stash bb row in imag slots: bb[t] = bf[2t+1] ----
#pragma unroll
    for (int k = 0; k < 16; k++) {
        int t = tid * 16 + k;
        bf[2 * t + 1] = bvals[k] * fac;
    }
    __syncthreads();

    // ---- interp bb ([xlo,xhi] grid, LL pts) onto ppm axis -> registers ----
    const float xlo = g_ppmr[0];
    const float xhi = g_ppmr[1];
    const float posmul = (float)(LL - 1) / (xhi - xlo);
    float val[PP / 256];
#pragma unroll
    for (int m = 0; m < PP / 256; m++) {
        int j = tid + m * 256;
        float x = g_ppm[j];
        float re = 0.0f;
        if (x >= xlo && x <= xhi) {
            float pos = (x - xlo) * posmul;
            int i = (int)floorf(pos);
            i = (i < 0) ? 0 : ((i > LL - 2) ? (LL - 2) : i);
            float fr = pos - (float)i;
            float s0 = bf[2 * i + 1], s1 = bf[2 * i + 3];
            re = s0 + (s1 - s0) * fr;
        }
        val[m] = re;
    }
    __syncthreads();   // all bb reads complete
#pragma unroll
    for (int m = 0; m < PP / 256; m++) {
        int j = tid + m * 256;
        buf[j] = make_float2(val[m], 0.0f);
    }
    __syncthreads();

    const float PIF = 3.14159265358979323846f;

    // ---- forward FFT: radix-2 DIF, natural -> bit-reversed ----
    for (int half = PP / 2; half >= 1; half >>= 1) {
        const float ang_base = -PIF / (float)half;
        for (int m = 0; m < PP / 512; m++) {
            int b = tid + m * 256;
            int j = b & (half - 1);
            int i = ((b & ~(half - 1)) << 1) | j;
            float2 a = buf[i];
            float2 c = buf[i + half];
            float2 s = make_float2(a.x + c.x, a.y + c.y);
            float2 d = make_float2(a.x - c.x, a.y - c.y);
            float sn, cn;
            __sincosf(ang_base * (float)j, &sn, &cn);
            buf[i] = s;
            buf[i + half] = make_float2(d.x * cn - d.y * sn, d.x * sn + d.y * cn);
        }
        __syncthreads();
    }

    // ---- analytic filter h at bit-reversed positions ----
#pragma unroll
    for (int m = 0; m < PP / 256; m++) {
        int idx = tid + m * 256;
        unsigned k = __brev((unsigned)idx) >> (32 - LOGP);
        float g = (k == 0u || k == (unsigned)(PP / 2)) ? 1.0f
                  : ((k < (unsigned)(PP / 2)) ? 2.0f : 0.0f);
        float2 a = buf[idx];
        buf[idx] = make_float2(a.x * g, a.y * g);
    }
    __syncthreads();

    // ---- inverse FFT: radix-2 DIT, bit-reversed -> natural ----
    for (int half = 1; half <= PP / 2; half <<= 1) {
        const float ang_base = PIF / (float)half;
        for (int m = 0; m < PP / 512; m++) {
            int b = tid + m * 256;
            int j = b & (half - 1);
            int i = ((b & ~(half - 1)) << 1) | j;
            float2 a = buf[i];
            float2 c = buf[i + half];
            float sn, cn;
            __sincosf(ang_base * (float)j, &sn, &cn);
            float2 cw = make_float2(c.x * cn - c.y * sn, c.x * sn + c.y * cn);
            buf[i] = make_float2(a.x + cw.x, a.y + cw.y);
            buf[i + half] = make_float2(a.x - cw.x, a.y - cw.y);
        }
        __syncthreads();
    }

    // ---- write FP32 outputs: out0 = flip(raw,-1), out1 = raw, each [N,2,P] ----
    const float invP = 1.0f / (float)PP;
    const size_t base1 = (size_t)NB * 2 * PP + (size_t)n * 2 * PP;  // raw
    const size_t base0 = (size_t)n * 2 * PP;                         // flipped
#pragma unroll
    for (int m = 0; m < PP / 256; m++) {
        int t = tid + m * 256;
        float2 a = buf[t];
        float re = a.x * invP;
        float im = a.y * invP;
        g_out[base1 + t]               = re;
        g_out[base1 + PP + t]          = im;
        g_out[base0 + (PP - 1 - t)]    = re;
        g_out[base0 + 2 * PP - 1 - t]  = im;
    }
}

extern "C" void kernel_launch(void* const* d_in, const int* in_sizes, int n_in,
                              void* d_out, int out_size, void* d_ws, size_t ws_size,
                              hipStream_t stream)
{
    const float* start = (const float*)d_in[0];
    const float* end_  = (const float*)d_in[1];
    const float* stdv  = (const float*)d_in[2];
    const float* lowb  = (const float*)d_in[3];
    const float* upb   = (const float*)d_in[4];
    const int*   win   = (const int*)d_in[5];
    const float* scl   = (const float*)d_in[6];
    const float* noise = (const float*)d_in[7];
    const float* omit  = (const float*)d_in[8];
    const float* ppm   = (const float*)d_in[9];
    const float* ppmr  = (const float*)d_in[10];
    float* out = (float*)d_out;

    hipLaunchKernelGGL(k_all, dim3(NB), dim3(256), 0, stream,
                       start, end_, stdv, lowb, upb, win, scl, noise, omit,
                       ppm, ppmr, out);
}

// Round 4
// 237.390 us; speedup vs baseline: 1.1864x; 1.1864x over previous
//
#include <hip/hip_runtime.h>

#define NB 1024
#define LL 4096
#define PP 8192

__device__ __forceinline__ float2 cadd(float2 a, float2 b){ return make_float2(a.x+b.x, a.y+b.y); }
__device__ __forceinline__ float2 csub(float2 a, float2 b){ return make_float2(a.x-b.x, a.y-b.y); }
__device__ __forceinline__ float2 cmul(float2 a, float2 b){ return make_float2(a.x*b.x - a.y*b.y, a.x*b.y + a.y*b.x); }

#define PIF 3.14159265358979323846f

// ---- forward radix-4 DIF stage, sub-block stride H (groups of 4H) ----
// Y0 = t0+t1; Y1 = (t2 - i t3)E; Y2 = (t0-t1)E^2; Y3 = (t2 + i t3)E^3,
// E = exp(-i*pi*j/(2H)).  Output digit d -> buf[i + d*H].
template<int H>
__device__ __forceinline__ void fwd_r4(float2* buf, int tid){
#pragma unroll
    for (int m = 0; m < PP/4/256; m++){
        int b = tid + m*256;
        int j = b & (H-1);
        int i = ((b & ~(H-1)) << 2) | j;
        float2 x0 = buf[i], x1 = buf[i+H], x2 = buf[i+2*H], x3 = buf[i+3*H];
        float2 t0 = cadd(x0,x2), t1 = cadd(x1,x3);
        float2 t2 = csub(x0,x2), t3 = csub(x1,x3);
        float2 y0 = cadd(t0,t1);
        float2 y2 = csub(t0,t1);
        float2 y1 = make_float2(t2.x + t3.y, t2.y - t3.x);   // t2 - i*t3
        float2 y3 = make_float2(t2.x - t3.y, t2.y + t3.x);   // t2 + i*t3
        if (H > 1){
            float sn, cn; __sincosf((-PIF/(2.0f*(float)H)) * (float)j, &sn, &cn);
            float2 E  = make_float2(cn, sn);
            float2 E2 = cmul(E,E);
            float2 E3 = cmul(E2,E);
            y1 = cmul(y1,E); y2 = cmul(y2,E2); y3 = cmul(y3,E3);
        }
        buf[i] = y0; buf[i+H] = y1; buf[i+2*H] = y2; buf[i+3*H] = y3;
    }
}

// ---- inverse radix-4 DIT stage (conjugate mirror of fwd_r4) ----
template<int H>
__device__ __forceinline__ void inv_r4(float2* buf, int tid){
#pragma unroll
    for (int m = 0; m < PP/4/256; m++){
        int b = tid + m*256;
        int j = b & (H-1);
        int i = ((b & ~(H-1)) << 2) | j;
        float2 z0 = buf[i], z1 = buf[i+H], z2 = buf[i+2*H], z3 = buf[i+3*H];
        if (H > 1){
            float sn, cn; __sincosf((PIF/(2.0f*(float)H)) * (float)j, &sn, &cn);
            float2 E  = make_float2(cn, sn);
            float2 E2 = cmul(E,E);
            float2 E3 = cmul(E2,E);
            z1 = cmul(z1,E); z2 = cmul(z2,E2); z3 = cmul(z3,E3);
        }
        float2 s0 = cadd(z0,z2), s1 = cadd(z1,z3);
        float2 s2 = csub(z0,z2), s3 = csub(z1,z3);
        buf[i]     = cadd(s0,s1);
        buf[i+2*H] = csub(s0,s1);
        buf[i+H]   = make_float2(s2.x - s3.y, s2.y + s3.x);  // s2 + i*s3
        buf[i+3*H] = make_float2(s2.x + s3.y, s2.y - s3.x);  // s2 - i*s3
    }
}

// ---- inverse first stage (H=1, j=0: twiddle-free) fused with Hilbert filter ----
// At DIF-output position p (radices [2,4,4,4,4,4,4]): k==0 <=> p==0,
// k==P/2 <=> p==2, k<P/2 <=> (p&3)<2.  gain = h(k)/P.  z3 gain always 0.
__device__ __forceinline__ void inv_first_filter(float2* buf, int tid){
    const float invP = 1.0f/(float)PP;
    const float inv2 = 2.0f*invP;
#pragma unroll
    for (int m = 0; m < PP/4/256; m++){
        int b = tid + m*256;
        int i = 4*b;
        float g0 = (i==0) ? invP : inv2;
        float2 z0 = buf[i];   z0.x*=g0;   z0.y*=g0;
        float2 z1 = buf[i+1]; z1.x*=inv2; z1.y*=inv2;
        float2 z2 = make_float2(0.0f,0.0f);
        if (i==0){ float2 t = buf[2]; z2 = make_float2(t.x*invP, t.y*invP); }
        // z3 = 0; s1 = s3 = z1
        float2 s0 = cadd(z0,z2);
        float2 s2 = csub(z0,z2);
        buf[i]   = cadd(s0,z1);
        buf[i+2] = csub(s0,z1);
        buf[i+1] = make_float2(s2.x - z1.y, s2.y + z1.x);
        buf[i+3] = make_float2(s2.x + z1.y, s2.y - z1.x);
    }
}

__global__ __launch_bounds__(256) void k_all(
    const float* __restrict__ g_start,
    const float* __restrict__ g_end,
    const float* __restrict__ g_std,
    const float* __restrict__ g_low,
    const float* __restrict__ g_up,
    const int*   __restrict__ g_win,
    const float* __restrict__ g_scale,
    const float* __restrict__ g_noise,
    const float* __restrict__ g_omit,
    const float* __restrict__ g_ppm,
    const float* __restrict__ g_ppmr,
    float* __restrict__ g_out)
{
    __shared__ float2 buf[PP];          // 64 KB exactly
    float* bf  = (float*)buf;
    float* cs  = bf;                    // 4097 floats
    float* tmp = bf + 4098;             // 256 floats
    float* shv = bf + 4356;             // 2 floats

    const int n   = blockIdx.x;
    const int tid = threadIdx.x;
    const float st = g_start[n];
    const float en = g_end[n];
    const float sd = g_std[n];
    const float lo = g_low[n];
    const float up = g_up[n];
    const int   w  = g_win[n];
    const float inv_nm1 = 1.0f / (float)(LL - 1);

    // ---- load 16 fp32 noise steps/thread ----
    float v[16];
    {
        const float4* p = (const float4*)(g_noise + (size_t)n * LL) + (size_t)tid * 4;
#pragma unroll
        for (int q = 0; q < 4; q++) {
            float4 t4 = p[q];
            v[4*q+0] = t4.x; v[4*q+1] = t4.y; v[4*q+2] = t4.z; v[4*q+3] = t4.w;
        }
    }
#pragma unroll
    for (int k = 0; k < 16; k++) v[k] = sd * (v[k] - 0.5f);

    // ---- scan #1: rand = inclusive cumsum(steps) ----
    float run = 0.0f;
#pragma unroll
    for (int k = 0; k < 16; k++) { run += v[k]; v[k] = run; }
    tmp[tid] = run; __syncthreads();
    for (int off = 1; off < 256; off <<= 1) {
        float a = tmp[tid];
        float b = (tid >= off) ? tmp[tid - off] : 0.0f;
        __syncthreads();
        tmp[tid] = a + b;
        __syncthreads();
    }
    float excl = tmp[tid] - run;
    if (tid == 0)   shv[0] = v[0];        // rand[0]
    if (tid == 255) shv[1] = tmp[255];    // rand[L-1]
    __syncthreads();
    const float r0 = shv[0], rT = shv[1];
    __syncthreads();

    // ---- detrend walk, min/max ----
    float del[16];
    float mx = -INFINITY, mn = INFINITY;
#pragma unroll
    for (int k = 0; k < 16; k++) {
        int t = tid * 16 + k;
        float d = (excl + v[k]) - (r0 + (rT - r0) * ((float)t * inv_nm1));
        del[k] = d;
        mx = fmaxf(mx, d); mn = fminf(mn, d);
    }
    tmp[tid] = mx; __syncthreads();
    for (int off = 128; off > 0; off >>= 1) { if (tid < off) tmp[tid] = fmaxf(tmp[tid], tmp[tid + off]); __syncthreads(); }
    mx = tmp[0]; __syncthreads();
    tmp[tid] = mn; __syncthreads();
    for (int off = 128; off > 0; off >>= 1) { if (tid < off) tmp[tid] = fminf(tmp[tid], tmp[tid + off]); __syncthreads(); }
    mn = tmp[0]; __syncthreads();

    const float qs = fmaxf(1.0f, (mx - mn) / (up - lo));

    // ---- squeeze + reflect + trend -> walk values ----
    float wv[16];
#pragma unroll
    for (int k = 0; k < 16; k++) {
        int t = tid * 16 + k;
        float tr  = st + (en - st) * ((float)t * inv_nm1);
        float ub  = up - tr;
        float lb2 = lo - tr;
        float d = del[k] / qs;
        float over = d - ub;
        d = (over >= 0.0f) ? (ub - over) : d;
        float under = lb2 - d;
        d = (under >= 0.0f) ? (lb2 + under) : d;
        wv[k] = tr + d;
    }

    // ---- scan #2: exclusive cumsum of walk -> cs[0..LL] ----
    run = 0.0f;
#pragma unroll
    for (int k = 0; k < 16; k++) { float x = wv[k]; run += x; wv[k] = run; }
    tmp[tid] = run; __syncthreads();
    for (int off = 1; off < 256; off <<= 1) {
        float a = tmp[tid];
        float b = (tid >= off) ? tmp[tid - off] : 0.0f;
        __syncthreads();
        tmp[tid] = a + b;
        __syncthreads();
    }
    float excl2 = tmp[tid] - run;
    float grand2 = tmp[255];
    __syncthreads();
#pragma unroll
    for (int k = 0; k < 16; k++) {
        int t = tid * 16 + k;
        cs[t] = excl2 + ((k == 0) ? 0.0f : wv[k - 1]);
    }
    if (tid == 255) cs[LL] = grand2;
    __syncthreads();

    // ---- box smooth (zero-padded via clamped exclusive cumsum) ----
    const int w2 = w / 2;
    const float invw = 1.0f / (float)w;
    float bvals[16];
#pragma unroll
    for (int k = 0; k < 16; k++) {
        int t  = tid * 16 + k;
        int li = t - w2;
        int hi = li + w;
        li = (li < 0) ? 0 : li;
        hi = (hi > LL) ? LL : hi;
        bvals[k] = (cs[hi] - cs[li]) * invw;
    }
    if (tid == 0)   shv[0] = bvals[0];
    if (tid == 255) shv[1] = bvals[15];
    __syncthreads();
    const float b0 = shv[0], bL = shv[1];

    // ---- detrend #2 + absmax-normalize ----
    float am = 0.0f;
#pragma unroll
    for (int k = 0; k < 16; k++) {
        int t = tid * 16 + k;
        bvals[k] -= b0 + (bL - b0) * ((float)t * inv_nm1);
        am = fmaxf(am, fabsf(bvals[k]));
    }
    tmp[tid] = am; __syncthreads();
    for (int off = 128; off > 0; off >>= 1) { if (tid < off) tmp[tid] = fmaxf(tmp[tid], tmp[tid + off]); __syncthreads(); }
    float denom = tmp[0];
    denom = (denom == 0.0f) ? 1.0f : denom;
    const float fac = g_omit[n] * g_scale[n] / denom;
    __syncthreads();   // all cs/tmp reads done before bb overwrites aliased slots

    // ---- stash bb row in imag slots: bb[t] = bf[2t+1] ----
#pragma unroll
    for (int k = 0; k < 16; k++) {
        int t = tid * 16 + k;
        bf[2 * t + 1] = bvals[k] * fac;
    }
    __syncthreads();

    // ---- interp bb ([xlo,xhi] grid, LL pts) onto ppm axis -> registers ----
    const float xlo = g_ppmr[0];
    const float xhi = g_ppmr[1];
    const float posmul = (float)(LL - 1) / (xhi - xlo);
    float val[PP / 256];
#pragma unroll
    for (int m = 0; m < PP / 256; m++) {
        int j = tid + m * 256;
        float x = g_ppm[j];
        float re = 0.0f;
        if (x >= xlo && x <= xhi) {
            float pos = (x - xlo) * posmul;
            int i = (int)floorf(pos);
            i = (i < 0) ? 0 : ((i > LL - 2) ? (LL - 2) : i);
            float fr = pos - (float)i;
            float s0 = bf[2 * i + 1], s1 = bf[2 * i + 3];
            re = s0 + (s1 - s0) * fr;
        }
        val[m] = re;
    }
    __syncthreads();   // all bb reads complete
#pragma unroll
    for (int m = 0; m < PP / 256; m++) {
        int j = tid + m * 256;
        buf[j] = make_float2(val[m], 0.0f);
    }
    __syncthreads();

    // ================= forward FFT: radix-2 (h=4096) + 6x radix-4 =================
#pragma unroll
    for (int m = 0; m < 16; m++) {
        int i = tid + m * 256;                      // 0..4095
        float2 a = buf[i], c = buf[i + 4096];
        float2 s = cadd(a, c);
        float2 d = csub(a, c);
        float sn, cn; __sincosf((-PIF / 4096.0f) * (float)i, &sn, &cn);
        buf[i] = s;
        buf[i + 4096] = cmul(d, make_float2(cn, sn));
    }
    __syncthreads();
    fwd_r4<1024>(buf, tid); __syncthreads();
    fwd_r4< 256>(buf, tid); __syncthreads();
    fwd_r4<  64>(buf, tid); __syncthreads();
    fwd_r4<  16>(buf, tid); __syncthreads();
    fwd_r4<   4>(buf, tid); __syncthreads();
    fwd_r4<   1>(buf, tid); __syncthreads();

    // ================= inverse FFT (filter + 1/P fused into first stage) =========
    inv_first_filter(buf, tid); __syncthreads();
    inv_r4<   4>(buf, tid); __syncthreads();
    inv_r4<  16>(buf, tid); __syncthreads();
    inv_r4<  64>(buf, tid); __syncthreads();
    inv_r4< 256>(buf, tid); __syncthreads();
    inv_r4<1024>(buf, tid); __syncthreads();
#pragma unroll
    for (int m = 0; m < 16; m++) {
        int i = tid + m * 256;
        float2 a = buf[i], c = buf[i + 4096];
        float sn, cn; __sincosf((PIF / 4096.0f) * (float)i, &sn, &cn);
        float2 u = cmul(c, make_float2(cn, sn));
        buf[i] = cadd(a, u);
        buf[i + 4096] = csub(a, u);
    }
    __syncthreads();

    // ---- write FP32 outputs: out0 = flip(raw,-1), out1 = raw, each [N,2,P] ----
    const size_t base1 = (size_t)NB * 2 * PP + (size_t)n * 2 * PP;  // raw
    const size_t base0 = (size_t)n * 2 * PP;                         // flipped
#pragma unroll
    for (int m = 0; m < PP / 256; m++) {
        int t = tid + m * 256;
        float2 a = buf[t];
        g_out[base1 + t]               = a.x;
        g_out[base1 + PP + t]          = a.y;
        g_out[base0 + (PP - 1 - t)]    = a.x;
        g_out[base0 + 2 * PP - 1 - t]  = a.y;
    }
}

extern "C" void kernel_launch(void* const* d_in, const int* in_sizes, int n_in,
                              void* d_out, int out_size, void* d_ws, size_t ws_size,
                              hipStream_t stream)
{
    const float* start = (const float*)d_in[0];
    const float* end_  = (const float*)d_in[1];
    const float* stdv  = (const float*)d_in[2];
    const float* lowb  = (const float*)d_in[3];
    const float* upb   = (const float*)d_in[4];
    const int*   win   = (const int*)d_in[5];
    const float* scl   = (const float*)d_in[6];
    const float* noise = (const float*)d_in[7];
    const float* omit  = (const float*)d_in[8];
    const float* ppm   = (const float*)d_in[9];
    const float* ppmr  = (const float*)d_in[10];
    float* out = (float*)d_out;

    hipLaunchKernelGGL(k_all, dim3(NB), dim3(256), 0, stream,
                       start, end_, stdv, lowb, upb, win, scl, noise, omit,
                       ppm, ppmr, out);
}